// Round 4
// baseline (4816.834 us; speedup 1.0000x reference)
//
#include <hip/hip_runtime.h>
#include <hip/hip_bf16.h>

#define NN 100000
#define NE 1600000
#define DIN 1000
#define BN_EPS 1e-3f

// output element offsets (concat of z, mu, logvar, de_feat, q, feat_x, gnn_z) — float32 out
#define OZ  ((size_t)0)
#define OMU ((size_t)NN*80)
#define OLV ((size_t)NN*96)
#define ODE ((size_t)NN*112)
#define OQ  ((size_t)NN*1112)
#define OFX ((size_t)NN*1127)
#define OGZ ((size_t)NN*1191)

__device__ __forceinline__ float elu_f(float x) { return x > 0.f ? x : expf(x) - 1.f; }

// Edge index may arrive as int32 or int64; logical element idx in flat (2*E) array.
__device__ __forceinline__ int edge_at(const void* ei, int is64, size_t idx) {
    if (is64) return (int)((const long long*)ei)[idx];
    return ((const int*)ei)[idx];
}

// ---------------- dtype detection ----------------
__global__ __launch_bounds__(256) void k_detect(const int* __restrict__ ei, int* __restrict__ flag) {
    __shared__ int nz;
    if (threadIdx.x == 0) nz = 0;
    __syncthreads();
    for (int i = threadIdx.x; i < 2048; i += 256)
        if (ei[2 * i + 1] != 0) nz = 1;
    __syncthreads();
    if (threadIdx.x == 0) flag[0] = (nz == 0) ? 1 : 0;  // 1 => int64
}

// ---------------- degree / edge norm ----------------
__global__ __launch_bounds__(256) void k_deg_init(float* __restrict__ deg) {
    int i = blockIdx.x * 256 + threadIdx.x;
    if (i < NN) deg[i] = 1.0f;
}

__global__ __launch_bounds__(256) void k_deg_accum(const void* __restrict__ ei, const int* __restrict__ flag,
                                                   float* __restrict__ deg) {
    const int is64 = flag[0];
    int e = blockIdx.x * 256 + threadIdx.x;
    if (e < NE) atomicAdd(&deg[edge_at(ei, is64, (size_t)NE + e)], 1.0f);
}

__global__ __launch_bounds__(256) void k_edge_w(const void* __restrict__ ei, const int* __restrict__ flag,
                                                const float* __restrict__ deg, float* __restrict__ ew) {
    const int is64 = flag[0];
    int e = blockIdx.x * 256 + threadIdx.x;
    if (e < NE) {
        int r = edge_at(ei, is64, e);
        int c = edge_at(ei, is64, (size_t)NE + e);
        ew[e] = rsqrtf(deg[r]) * rsqrtf(deg[c]);
    }
}

// ---------------- encoder L0: x[N,1000] @ w[1000,256] + BN + ELU ----------------
__global__ __launch_bounds__(256) void k_enc0(
    const float* __restrict__ x, const float* __restrict__ w, const float* __restrict__ bias,
    const float* __restrict__ g, const float* __restrict__ bb,
    const float* __restrict__ m, const float* __restrict__ v,
    float* __restrict__ h1)
{
    __shared__ float xs[32 * 200];
    const int t = threadIdx.x;
    const int row0 = blockIdx.x * 32;
    const int j0 = t & 63;
    const int r0 = (t >> 6) * 8;
    float acc[8][4];
    #pragma unroll
    for (int r = 0; r < 8; ++r) {
        #pragma unroll
        for (int c = 0; c < 4; ++c) acc[r][c] = 0.f;
    }

    for (int kt = 0; kt < 5; ++kt) {
        const int k0 = kt * 200;
        __syncthreads();
        for (int idx = t; idx < 1600; idx += 256) {
            const int r = idx / 50, c4 = idx % 50;
            *reinterpret_cast<float4*>(&xs[r * 200 + c4 * 4]) =
                *reinterpret_cast<const float4*>(&x[(size_t)(row0 + r) * DIN + k0 + c4 * 4]);
        }
        __syncthreads();
        #pragma unroll 1
        for (int k = 0; k < 200; k += 4) {
            float wv[4][4];
            #pragma unroll
            for (int kk = 0; kk < 4; ++kk) {
                #pragma unroll
                for (int c = 0; c < 4; ++c)
                    wv[kk][c] = w[(size_t)(k0 + k + kk) * 256 + j0 + 64 * c];
            }
            #pragma unroll
            for (int r = 0; r < 8; ++r) {
                const float4 xv = *reinterpret_cast<const float4*>(&xs[(r0 + r) * 200 + k]);
                const float xa[4] = {xv.x, xv.y, xv.z, xv.w};
                #pragma unroll
                for (int kk = 0; kk < 4; ++kk) {
                    #pragma unroll
                    for (int c = 0; c < 4; ++c)
                        acc[r][c] = fmaf(xa[kk], wv[kk][c], acc[r][c]);
                }
            }
        }
    }
    #pragma unroll
    for (int c = 0; c < 4; ++c) {
        const int j = j0 + 64 * c;
        const float sc = rsqrtf(v[j] + BN_EPS) * g[j];
        const float sh = (bias[j] - m[j]) * sc + bb[j];
        #pragma unroll
        for (int r = 0; r < 8; ++r) {
            const float y = acc[r][c] * sc + sh;
            h1[(size_t)(row0 + r0 + r) * 256 + j] = elu_f(y);
        }
    }
}

// ---------------- encoder L1: h1[N,256] @ w[256,64] + BN + ELU -> feat, out ----------------
__global__ __launch_bounds__(256) void k_enc1(
    const float* __restrict__ h1, const float* __restrict__ w, const float* __restrict__ bias,
    const float* __restrict__ g, const float* __restrict__ bb,
    const float* __restrict__ m, const float* __restrict__ v,
    float* __restrict__ feat, float* __restrict__ out)
{
    __shared__ float hs[32 * 256];
    const int t = threadIdx.x;
    const int row0 = blockIdx.x * 32;
    const int j0 = t & 31;
    const int r0 = (t >> 5) * 4;
    float acc[4][2] = {};
    for (int idx = t; idx < 2048; idx += 256) {
        const int r = idx >> 6, c4 = idx & 63;
        *reinterpret_cast<float4*>(&hs[r * 256 + c4 * 4]) =
            *reinterpret_cast<const float4*>(&h1[(size_t)(row0 + r) * 256 + c4 * 4]);
    }
    __syncthreads();
    #pragma unroll 1
    for (int k = 0; k < 256; k += 4) {
        float wv[4][2];
        #pragma unroll
        for (int kk = 0; kk < 4; ++kk) {
            wv[kk][0] = w[(k + kk) * 64 + j0];
            wv[kk][1] = w[(k + kk) * 64 + j0 + 32];
        }
        #pragma unroll
        for (int r = 0; r < 4; ++r) {
            const float4 xv = *reinterpret_cast<const float4*>(&hs[(r0 + r) * 256 + k]);
            const float xa[4] = {xv.x, xv.y, xv.z, xv.w};
            #pragma unroll
            for (int kk = 0; kk < 4; ++kk) {
                acc[r][0] = fmaf(xa[kk], wv[kk][0], acc[r][0]);
                acc[r][1] = fmaf(xa[kk], wv[kk][1], acc[r][1]);
            }
        }
    }
    #pragma unroll
    for (int c = 0; c < 2; ++c) {
        const int j = j0 + 32 * c;
        const float sc = rsqrtf(v[j] + BN_EPS) * g[j];
        const float sh = (bias[j] - m[j]) * sc + bb[j];
        #pragma unroll
        for (int r = 0; r < 4; ++r) {
            const size_t rowi = row0 + r0 + r;
            const float y = elu_f(acc[r][c] * sc + sh);
            feat[rowi * 64 + j] = y;
            out[OFX + rowi * 64 + j] = y;
            out[OZ + rowi * 80 + j] = y;
        }
    }
}

// ---------------- GCN projection: feat[N,64] @ conv_w[64,128]; init agg with self-loop+bias ----------------
__global__ __launch_bounds__(256) void k_conv_proj(
    const float* __restrict__ feat, const float* __restrict__ w, const float* __restrict__ cb,
    const float* __restrict__ deg,
    float* __restrict__ hc, float* __restrict__ agg)
{
    __shared__ float fs[32 * 64];
    const int t = threadIdx.x;
    const int row0 = blockIdx.x * 32;
    const int j0 = t & 63;
    const int r0 = (t >> 6) * 8;
    float acc[8][2] = {};
    for (int idx = t; idx < 512; idx += 256) {
        const int r = idx >> 4, c4 = idx & 15;
        *reinterpret_cast<float4*>(&fs[r * 64 + c4 * 4]) =
            *reinterpret_cast<const float4*>(&feat[(size_t)(row0 + r) * 64 + c4 * 4]);
    }
    __syncthreads();
    #pragma unroll 1
    for (int k = 0; k < 64; k += 4) {
        float wv[4][2];
        #pragma unroll
        for (int kk = 0; kk < 4; ++kk) {
            wv[kk][0] = w[(k + kk) * 128 + j0];
            wv[kk][1] = w[(k + kk) * 128 + j0 + 64];
        }
        #pragma unroll
        for (int r = 0; r < 8; ++r) {
            const float4 xv = *reinterpret_cast<const float4*>(&fs[(r0 + r) * 64 + k]);
            const float xa[4] = {xv.x, xv.y, xv.z, xv.w};
            #pragma unroll
            for (int kk = 0; kk < 4; ++kk) {
                acc[r][0] = fmaf(xa[kk], wv[kk][0], acc[r][0]);
                acc[r][1] = fmaf(xa[kk], wv[kk][1], acc[r][1]);
            }
        }
    }
    #pragma unroll
    for (int r = 0; r < 8; ++r) {
        const size_t rowi = row0 + r0 + r;
        const float dinv = 1.0f / deg[rowi];
        #pragma unroll
        for (int c = 0; c < 2; ++c) {
            const int j = j0 + 64 * c;
            const float val = acc[r][c];
            hc[rowi * 128 + j] = val;
            agg[rowi * 128 + j] = val * dinv + cb[j];
        }
    }
}

// ---------------- GCN scatter: agg[col] += hc[row]*ew, 128 feats ----------------
__global__ __launch_bounds__(256) void k_conv_scatter(
    const void* __restrict__ ei, const int* __restrict__ flag, const float* __restrict__ ew,
    const float* __restrict__ hc, float* __restrict__ agg)
{
    const int is64 = flag[0];
    const int tid = blockIdx.x * 256 + threadIdx.x;
    const int e = tid >> 5;
    const int c = tid & 31;
    if (e >= NE) return;
    const int r = edge_at(ei, is64, e);
    const int cl = edge_at(ei, is64, (size_t)NE + e);
    const float wgt = ew[e];
    const float4 h4 = *reinterpret_cast<const float4*>(&hc[(size_t)r * 128 + c * 4]);
    float* dst = &agg[(size_t)cl * 128 + c * 4];
    atomicAdd(dst + 0, h4.x * wgt);
    atomicAdd(dst + 1, h4.y * wgt);
    atomicAdd(dst + 2, h4.z * wgt);
    atomicAdd(dst + 3, h4.w * wgt);
}

// ---------------- BN + ReLU in place on agg[N,128] ----------------
__global__ __launch_bounds__(256) void k_bn_relu(
    float* __restrict__ a,
    const float* __restrict__ g, const float* __restrict__ bb,
    const float* __restrict__ m, const float* __restrict__ v)
{
    const size_t i4 = (size_t)blockIdx.x * 256 + threadIdx.x;
    if (i4 >= (size_t)NN * 32) return;
    const int j0 = (int)((i4 & 31) * 4);
    float4 val = *reinterpret_cast<float4*>(&a[i4 * 4]);
    float o[4] = {val.x, val.y, val.z, val.w};
    #pragma unroll
    for (int k = 0; k < 4; ++k) {
        const int j = j0 + k;
        const float sc = rsqrtf(v[j] + BN_EPS) * g[j];
        const float sh = bb[j] - m[j] * sc;
        o[k] = fmaxf(o[k] * sc + sh, 0.f);
    }
    *reinterpret_cast<float4*>(&a[i4 * 4]) = make_float4(o[0], o[1], o[2], o[3]);
}

// ---------------- mean|logvar projection: c[N,128] @ [mw|lw][128,16+16]; init agg2 ----------------
__global__ __launch_bounds__(256) void k_mlp_proj(
    const float* __restrict__ c, const float* __restrict__ mw, const float* __restrict__ mb,
    const float* __restrict__ lw, const float* __restrict__ lb,
    const float* __restrict__ deg,
    float* __restrict__ m2, float* __restrict__ agg2)
{
    __shared__ float cs[32 * 128];
    const int t = threadIdx.x;
    const int row0 = blockIdx.x * 32;
    const int j0 = t & 15;
    const int r0 = (t >> 4) * 2;
    float acc[2][2] = {};
    for (int idx = t; idx < 1024; idx += 256) {
        const int r = idx >> 5, c4 = idx & 31;
        *reinterpret_cast<float4*>(&cs[r * 128 + c4 * 4]) =
            *reinterpret_cast<const float4*>(&c[(size_t)(row0 + r) * 128 + c4 * 4]);
    }
    __syncthreads();
    #pragma unroll 1
    for (int k = 0; k < 128; k += 4) {
        float wv[4][2];
        #pragma unroll
        for (int kk = 0; kk < 4; ++kk) {
            wv[kk][0] = mw[(k + kk) * 16 + j0];
            wv[kk][1] = lw[(k + kk) * 16 + j0];
        }
        #pragma unroll
        for (int r = 0; r < 2; ++r) {
            const float4 xv = *reinterpret_cast<const float4*>(&cs[(r0 + r) * 128 + k]);
            const float xa[4] = {xv.x, xv.y, xv.z, xv.w};
            #pragma unroll
            for (int kk = 0; kk < 4; ++kk) {
                acc[r][0] = fmaf(xa[kk], wv[kk][0], acc[r][0]);
                acc[r][1] = fmaf(xa[kk], wv[kk][1], acc[r][1]);
            }
        }
    }
    #pragma unroll
    for (int r = 0; r < 2; ++r) {
        const size_t rowi = row0 + r0 + r;
        const float dinv = 1.0f / deg[rowi];
        m2[rowi * 32 + j0] = acc[r][0];
        m2[rowi * 32 + 16 + j0] = acc[r][1];
        agg2[rowi * 32 + j0] = acc[r][0] * dinv + mb[j0];
        agg2[rowi * 32 + 16 + j0] = acc[r][1] * dinv + lb[j0];
    }
}

// ---------------- mean|logvar scatter: 32 feats ----------------
__global__ __launch_bounds__(256) void k_mlp_scatter(
    const void* __restrict__ ei, const int* __restrict__ flag, const float* __restrict__ ew,
    const float* __restrict__ m2, float* __restrict__ agg2)
{
    const int is64 = flag[0];
    const int tid = blockIdx.x * 256 + threadIdx.x;
    const int e = tid >> 3;
    const int c = tid & 7;
    if (e >= NE) return;
    const int r = edge_at(ei, is64, e);
    const int cl = edge_at(ei, is64, (size_t)NE + e);
    const float wgt = ew[e];
    const float4 h4 = *reinterpret_cast<const float4*>(&m2[(size_t)r * 32 + c * 4]);
    float* dst = &agg2[(size_t)cl * 32 + c * 4];
    atomicAdd(dst + 0, h4.x * wgt);
    atomicAdd(dst + 1, h4.y * wgt);
    atomicAdd(dst + 2, h4.z * wgt);
    atomicAdd(dst + 3, h4.w * wgt);
}

// ---------------- finalize: mu/logvar/z writes, dec0, dec1, q ----------------
__global__ __launch_bounds__(256) void k_final(
    const float* __restrict__ feat, const float* __restrict__ agg2,
    const float* __restrict__ d0w, const float* __restrict__ d0b,
    const float* __restrict__ g, const float* __restrict__ bb,
    const float* __restrict__ m, const float* __restrict__ v,
    const float* __restrict__ d1w, const float* __restrict__ d1b,
    const float* __restrict__ cluster,
    float* __restrict__ out)
{
    __shared__ float zs[8][80];
    __shared__ float d0s[8][64];
    __shared__ float qs[8][15];
    const int t = threadIdx.x;
    const int row0 = blockIdx.x * 8;

    for (int idx = t; idx < 512; idx += 256) {
        const int r = idx >> 6, k = idx & 63;
        zs[r][k] = feat[(size_t)(row0 + r) * 64 + k];
    }
    if (t < 128) {
        const int r = t >> 4, k = t & 15;
        const size_t rowi = row0 + r;
        const float muv = agg2[rowi * 32 + k];
        const float lv = agg2[rowi * 32 + 16 + k];
        zs[r][64 + k] = muv;
        out[OMU + rowi * 16 + k] = muv;
        out[OGZ + rowi * 16 + k] = muv;
        out[OZ + rowi * 80 + 64 + k] = muv;
        out[OLV + rowi * 16 + k] = lv;
    }
    __syncthreads();

    // dec0: d0 = ELU(BN(z @ d0w + d0b))
    for (int idx = t; idx < 512; idx += 256) {
        const int r = idx >> 6, n = idx & 63;
        float acc = 0.f;
        #pragma unroll
        for (int k = 0; k < 80; k += 4) {
            const float4 zv = *reinterpret_cast<const float4*>(&zs[r][k]);
            acc = fmaf(zv.x, d0w[(k + 0) * 64 + n], acc);
            acc = fmaf(zv.y, d0w[(k + 1) * 64 + n], acc);
            acc = fmaf(zv.z, d0w[(k + 2) * 64 + n], acc);
            acc = fmaf(zv.w, d0w[(k + 3) * 64 + n], acc);
        }
        acc += d0b[n];
        const float sc = rsqrtf(v[n] + BN_EPS) * g[n];
        d0s[r][n] = elu_f((acc - m[n]) * sc + bb[n]);
    }
    __syncthreads();

    // dec1: de_feat = d0 @ d1w + d1b
    float accC[8][4];
    #pragma unroll
    for (int r = 0; r < 8; ++r) {
        #pragma unroll
        for (int c = 0; c < 4; ++c) accC[r][c] = 0.f;
    }
    int colc[4];
    #pragma unroll
    for (int cj = 0; cj < 4; ++cj) {
        const int col = t + 256 * cj;
        colc[cj] = col < DIN ? col : DIN - 1;
    }
    #pragma unroll 1
    for (int n4 = 0; n4 < 64; n4 += 4) {
        float da[8][4];
        #pragma unroll
        for (int r = 0; r < 8; ++r) {
            const float4 dv = *reinterpret_cast<const float4*>(&d0s[r][n4]);
            da[r][0] = dv.x; da[r][1] = dv.y; da[r][2] = dv.z; da[r][3] = dv.w;
        }
        #pragma unroll
        for (int kk = 0; kk < 4; ++kk) {
            float wv[4];
            #pragma unroll
            for (int cj = 0; cj < 4; ++cj)
                wv[cj] = d1w[(size_t)(n4 + kk) * DIN + colc[cj]];
            #pragma unroll
            for (int r = 0; r < 8; ++r) {
                #pragma unroll
                for (int cj = 0; cj < 4; ++cj)
                    accC[r][cj] = fmaf(da[r][kk], wv[cj], accC[r][cj]);
            }
        }
    }
    #pragma unroll
    for (int cj = 0; cj < 4; ++cj) {
        const int col = t + 256 * cj;
        if (col < DIN) {
            const float bv = d1b[col];
            #pragma unroll
            for (int r = 0; r < 8; ++r)
                out[ODE + (size_t)(row0 + r) * DIN + col] = accC[r][cj] + bv;
        }
    }

    // student-t q
    if (t < 120) {
        const int r = t / 15, c = t % 15;
        float zz = 0.f, cc = 0.f, dot = 0.f;
        #pragma unroll 1
        for (int k = 0; k < 80; ++k) {
            const float zv = zs[r][k];
            const float cv = cluster[c * 80 + k];
            zz = fmaf(zv, zv, zz);
            cc = fmaf(cv, cv, cc);
            dot = fmaf(zv, cv, dot);
        }
        const float dist = fmaxf(zz + cc - 2.f * dot, 0.f);
        qs[r][c] = powf(1.0f / (1.0f + dist / 0.9f + 1e-8f), 0.95f);
    }
    __syncthreads();
    if (t < 120) {
        const int r = t / 15, c = t % 15;
        float s = 0.f;
        #pragma unroll
        for (int c2 = 0; c2 < 15; ++c2) s += qs[r][c2];
        out[OQ + (size_t)(row0 + r) * 15 + c] = qs[r][c] / s;
    }
}

extern "C" void kernel_launch(void* const* d_in, const int* in_sizes, int n_in,
                              void* d_out, int out_size, void* d_ws, size_t ws_size,
                              hipStream_t stream)
{
    const float* x       = (const float*)d_in[0];
    const void*  ei      = d_in[1];
    const float* enc0_w  = (const float*)d_in[2];
    const float* enc0_b  = (const float*)d_in[3];
    const float* enc0_g  = (const float*)d_in[4];
    const float* enc0_bb = (const float*)d_in[5];
    const float* enc0_m  = (const float*)d_in[6];
    const float* enc0_v  = (const float*)d_in[7];
    const float* enc1_w  = (const float*)d_in[8];
    const float* enc1_b  = (const float*)d_in[9];
    const float* enc1_g  = (const float*)d_in[10];
    const float* enc1_bb = (const float*)d_in[11];
    const float* enc1_m  = (const float*)d_in[12];
    const float* enc1_v  = (const float*)d_in[13];
    const float* conv_w  = (const float*)d_in[14];
    const float* conv_b  = (const float*)d_in[15];
    const float* conv_g  = (const float*)d_in[16];
    const float* conv_bb = (const float*)d_in[17];
    const float* conv_m  = (const float*)d_in[18];
    const float* conv_v  = (const float*)d_in[19];
    const float* mean_w  = (const float*)d_in[20];
    const float* mean_b  = (const float*)d_in[21];
    const float* logvar_w = (const float*)d_in[22];
    const float* logvar_b = (const float*)d_in[23];
    const float* dec0_w  = (const float*)d_in[24];
    const float* dec0_b  = (const float*)d_in[25];
    const float* dec0_g  = (const float*)d_in[26];
    const float* dec0_bb = (const float*)d_in[27];
    const float* dec0_m  = (const float*)d_in[28];
    const float* dec0_v  = (const float*)d_in[29];
    const float* dec1_w  = (const float*)d_in[30];
    const float* dec1_b  = (const float*)d_in[31];
    const float* cluster = (const float*)d_in[32];

    float* ws = (float*)d_ws;
    float* deg  = ws;                              // N
    float* feat = ws + NN;                         // 64N
    float* A    = ws + (size_t)65 * NN;            // 256N (h1; later hc+agg; later m2+agg2)
    float* ew   = ws + (size_t)321 * NN;           // E
    int*   flag = (int*)(ws + (size_t)321 * NN + NE);  // 1
    float* h1   = A;
    float* hc   = A;
    float* agg  = A + (size_t)128 * NN;
    float* m2   = A;
    float* agg2 = A + (size_t)32 * NN;

    float* out = (float*)d_out;

    k_detect<<<1, 256, 0, stream>>>((const int*)ei, flag);
    k_deg_init<<<(NN + 255) / 256, 256, 0, stream>>>(deg);
    k_deg_accum<<<NE / 256, 256, 0, stream>>>(ei, flag, deg);
    k_edge_w<<<NE / 256, 256, 0, stream>>>(ei, flag, deg, ew);

    k_enc0<<<NN / 32, 256, 0, stream>>>(x, enc0_w, enc0_b, enc0_g, enc0_bb, enc0_m, enc0_v, h1);
    k_enc1<<<NN / 32, 256, 0, stream>>>(h1, enc1_w, enc1_b, enc1_g, enc1_bb, enc1_m, enc1_v, feat, out);

    k_conv_proj<<<NN / 32, 256, 0, stream>>>(feat, conv_w, conv_b, deg, hc, agg);
    k_conv_scatter<<<(NE * 32) / 256, 256, 0, stream>>>(ei, flag, ew, hc, agg);
    k_bn_relu<<<(NN * 32) / 256, 256, 0, stream>>>(agg, conv_g, conv_bb, conv_m, conv_v);

    k_mlp_proj<<<NN / 32, 256, 0, stream>>>(agg, mean_w, mean_b, logvar_w, logvar_b, deg, m2, agg2);
    k_mlp_scatter<<<(NE * 8) / 256, 256, 0, stream>>>(ei, flag, ew, m2, agg2);

    k_final<<<NN / 8, 256, 0, stream>>>(feat, agg2, dec0_w, dec0_b, dec0_g, dec0_bb, dec0_m, dec0_v,
                                        dec1_w, dec1_b, cluster, out);
}

// Round 6
// 1792.063 us; speedup vs baseline: 2.6879x; 2.6879x over previous
//
#include <hip/hip_runtime.h>
#include <hip/hip_bf16.h>

#define NN 100000
#define NE 1600000
#define DIN 1000
#define BN_EPS 1e-3f
#define NB 391   // ceil(NN/256)

// output element offsets (concat of z, mu, logvar, de_feat, q, feat_x, gnn_z) — float32 out
#define OZ  ((size_t)0)
#define OMU ((size_t)NN*80)
#define OLV ((size_t)NN*96)
#define ODE ((size_t)NN*112)
#define OQ  ((size_t)NN*1112)
#define OFX ((size_t)NN*1127)
#define OGZ ((size_t)NN*1191)

__device__ __forceinline__ float elu_f(float x) { return x > 0.f ? x : expf(x) - 1.f; }

// Edge index may arrive as int32 or int64; logical element idx in flat (2*E) array.
__device__ __forceinline__ int edge_at(const void* ei, int is64, size_t idx) {
    if (is64) return (int)((const long long*)ei)[idx];
    return ((const int*)ei)[idx];
}

// ---------------- dtype detection ----------------
__global__ __launch_bounds__(256) void k_detect(const int* __restrict__ ei, int* __restrict__ flag) {
    __shared__ int nz;
    if (threadIdx.x == 0) nz = 0;
    __syncthreads();
    for (int i = threadIdx.x; i < 2048; i += 256)
        if (ei[2 * i + 1] != 0) nz = 1;
    __syncthreads();
    if (threadIdx.x == 0) flag[0] = (nz == 0) ? 1 : 0;  // 1 => int64
}

// ---------------- degree ----------------
__global__ __launch_bounds__(256) void k_deg_init(float* __restrict__ deg) {
    int i = blockIdx.x * 256 + threadIdx.x;
    if (i < NN) deg[i] = 1.0f;
}

__global__ __launch_bounds__(256) void k_deg_accum(const void* __restrict__ ei, const int* __restrict__ flag,
                                                   float* __restrict__ deg) {
    const int is64 = flag[0];
    int e = blockIdx.x * 256 + threadIdx.x;
    if (e < NE) atomicAdd(&deg[edge_at(ei, is64, (size_t)NE + e)], 1.0f);
}

// ---------------- CSR build: exclusive scan of in-edge counts ----------------
__global__ __launch_bounds__(256) void k_scan1(const float* __restrict__ deg, int* __restrict__ off,
                                               int* __restrict__ bsum, int* __restrict__ cursor) {
    __shared__ int s[256];
    const int t = threadIdx.x;
    const int i = blockIdx.x * 256 + t;
    const int vv = (i < NN) ? ((int)deg[i]) - 1 : 0;
    if (i < NN) cursor[i] = 0;
    s[t] = vv;
    __syncthreads();
    for (int d = 1; d < 256; d <<= 1) {
        const int u = (t >= d) ? s[t - d] : 0;
        __syncthreads();
        s[t] += u;
        __syncthreads();
    }
    if (i < NN) off[i] = s[t] - vv;           // exclusive, pre-block-offset
    if (t == 255) bsum[blockIdx.x] = s[t];    // block total
}

__global__ __launch_bounds__(512) void k_scan2(int* __restrict__ bsum) {
    __shared__ int s[512];
    const int t = threadIdx.x;
    const int vv = (t < NB) ? bsum[t] : 0;
    s[t] = vv;
    __syncthreads();
    for (int d = 1; d < 512; d <<= 1) {
        const int u = (t >= d) ? s[t - d] : 0;
        __syncthreads();
        s[t] += u;
        __syncthreads();
    }
    if (t < NB) bsum[t] = s[t] - vv;          // exclusive block prefix
}

__global__ __launch_bounds__(256) void k_scan3(int* __restrict__ off, const int* __restrict__ bsum) {
    const int i = blockIdx.x * 256 + threadIdx.x;
    if (i < NN) off[i] += bsum[blockIdx.x];
}

__global__ __launch_bounds__(256) void k_fill(const void* __restrict__ ei, const int* __restrict__ flag,
                                              const float* __restrict__ deg, const int* __restrict__ off,
                                              int* __restrict__ cursor,
                                              int* __restrict__ csr_src, float* __restrict__ csr_w) {
    const int is64 = flag[0];
    const int e = blockIdx.x * 256 + threadIdx.x;
    if (e >= NE) return;
    const int r = edge_at(ei, is64, e);
    const int c = edge_at(ei, is64, (size_t)NE + e);
    const float w = rsqrtf(deg[r]) * rsqrtf(deg[c]);
    const int p = atomicAdd(&cursor[c], 1);
    const int slot = off[c] + p;
    csr_src[slot] = r;
    csr_w[slot] = w;
}

// ---------------- encoder L0: x[N,1000] @ w[1000,256] + BN + ELU ----------------
__global__ __launch_bounds__(256) void k_enc0(
    const float* __restrict__ x, const float* __restrict__ w, const float* __restrict__ bias,
    const float* __restrict__ g, const float* __restrict__ bb,
    const float* __restrict__ m, const float* __restrict__ v,
    float* __restrict__ h1)
{
    __shared__ float xs[32 * 200];
    const int t = threadIdx.x;
    const int row0 = blockIdx.x * 32;
    const int j0 = t & 63;
    const int r0 = (t >> 6) * 8;
    float acc[8][4];
    #pragma unroll
    for (int r = 0; r < 8; ++r) {
        #pragma unroll
        for (int c = 0; c < 4; ++c) acc[r][c] = 0.f;
    }

    for (int kt = 0; kt < 5; ++kt) {
        const int k0 = kt * 200;
        __syncthreads();
        for (int idx = t; idx < 1600; idx += 256) {
            const int r = idx / 50, c4 = idx % 50;
            *reinterpret_cast<float4*>(&xs[r * 200 + c4 * 4]) =
                *reinterpret_cast<const float4*>(&x[(size_t)(row0 + r) * DIN + k0 + c4 * 4]);
        }
        __syncthreads();
        #pragma unroll 1
        for (int k = 0; k < 200; k += 4) {
            float wv[4][4];
            #pragma unroll
            for (int kk = 0; kk < 4; ++kk) {
                #pragma unroll
                for (int c = 0; c < 4; ++c)
                    wv[kk][c] = w[(size_t)(k0 + k + kk) * 256 + j0 + 64 * c];
            }
            #pragma unroll
            for (int r = 0; r < 8; ++r) {
                const float4 xv = *reinterpret_cast<const float4*>(&xs[(r0 + r) * 200 + k]);
                const float xa[4] = {xv.x, xv.y, xv.z, xv.w};
                #pragma unroll
                for (int kk = 0; kk < 4; ++kk) {
                    #pragma unroll
                    for (int c = 0; c < 4; ++c)
                        acc[r][c] = fmaf(xa[kk], wv[kk][c], acc[r][c]);
                }
            }
        }
    }
    #pragma unroll
    for (int c = 0; c < 4; ++c) {
        const int j = j0 + 64 * c;
        const float sc = rsqrtf(v[j] + BN_EPS) * g[j];
        const float sh = (bias[j] - m[j]) * sc + bb[j];
        #pragma unroll
        for (int r = 0; r < 8; ++r) {
            const float y = acc[r][c] * sc + sh;
            h1[(size_t)(row0 + r0 + r) * 256 + j] = elu_f(y);
        }
    }
}

// ---------------- encoder L1: h1[N,256] @ w[256,64] + BN + ELU -> feat, out ----------------
__global__ __launch_bounds__(256) void k_enc1(
    const float* __restrict__ h1, const float* __restrict__ w, const float* __restrict__ bias,
    const float* __restrict__ g, const float* __restrict__ bb,
    const float* __restrict__ m, const float* __restrict__ v,
    float* __restrict__ feat, float* __restrict__ out)
{
    __shared__ float hs[32 * 256];
    const int t = threadIdx.x;
    const int row0 = blockIdx.x * 32;
    const int j0 = t & 31;
    const int r0 = (t >> 5) * 4;
    float acc[4][2] = {};
    for (int idx = t; idx < 2048; idx += 256) {
        const int r = idx >> 6, c4 = idx & 63;
        *reinterpret_cast<float4*>(&hs[r * 256 + c4 * 4]) =
            *reinterpret_cast<const float4*>(&h1[(size_t)(row0 + r) * 256 + c4 * 4]);
    }
    __syncthreads();
    #pragma unroll 1
    for (int k = 0; k < 256; k += 4) {
        float wv[4][2];
        #pragma unroll
        for (int kk = 0; kk < 4; ++kk) {
            wv[kk][0] = w[(k + kk) * 64 + j0];
            wv[kk][1] = w[(k + kk) * 64 + j0 + 32];
        }
        #pragma unroll
        for (int r = 0; r < 4; ++r) {
            const float4 xv = *reinterpret_cast<const float4*>(&hs[(r0 + r) * 256 + k]);
            const float xa[4] = {xv.x, xv.y, xv.z, xv.w};
            #pragma unroll
            for (int kk = 0; kk < 4; ++kk) {
                acc[r][0] = fmaf(xa[kk], wv[kk][0], acc[r][0]);
                acc[r][1] = fmaf(xa[kk], wv[kk][1], acc[r][1]);
            }
        }
    }
    #pragma unroll
    for (int c = 0; c < 2; ++c) {
        const int j = j0 + 32 * c;
        const float sc = rsqrtf(v[j] + BN_EPS) * g[j];
        const float sh = (bias[j] - m[j]) * sc + bb[j];
        #pragma unroll
        for (int r = 0; r < 4; ++r) {
            const size_t rowi = row0 + r0 + r;
            const float y = elu_f(acc[r][c] * sc + sh);
            feat[rowi * 64 + j] = y;
            out[OFX + rowi * 64 + j] = y;
            out[OZ + rowi * 80 + j] = y;
        }
    }
}

// ---------------- GCN projection: feat[N,64] @ conv_w[64,128] -> hc ----------------
__global__ __launch_bounds__(256) void k_conv_proj(
    const float* __restrict__ feat, const float* __restrict__ w,
    float* __restrict__ hc)
{
    __shared__ float fs[32 * 64];
    const int t = threadIdx.x;
    const int row0 = blockIdx.x * 32;
    const int j0 = t & 63;
    const int r0 = (t >> 6) * 8;
    float acc[8][2] = {};
    for (int idx = t; idx < 512; idx += 256) {
        const int r = idx >> 4, c4 = idx & 15;
        *reinterpret_cast<float4*>(&fs[r * 64 + c4 * 4]) =
            *reinterpret_cast<const float4*>(&feat[(size_t)(row0 + r) * 64 + c4 * 4]);
    }
    __syncthreads();
    #pragma unroll 1
    for (int k = 0; k < 64; k += 4) {
        float wv[4][2];
        #pragma unroll
        for (int kk = 0; kk < 4; ++kk) {
            wv[kk][0] = w[(k + kk) * 128 + j0];
            wv[kk][1] = w[(k + kk) * 128 + j0 + 64];
        }
        #pragma unroll
        for (int r = 0; r < 8; ++r) {
            const float4 xv = *reinterpret_cast<const float4*>(&fs[(r0 + r) * 64 + k]);
            const float xa[4] = {xv.x, xv.y, xv.z, xv.w};
            #pragma unroll
            for (int kk = 0; kk < 4; ++kk) {
                acc[r][0] = fmaf(xa[kk], wv[kk][0], acc[r][0]);
                acc[r][1] = fmaf(xa[kk], wv[kk][1], acc[r][1]);
            }
        }
    }
    #pragma unroll
    for (int r = 0; r < 8; ++r) {
        const size_t rowi = row0 + r0 + r;
        hc[rowi * 128 + j0] = acc[r][0];
        hc[rowi * 128 + j0 + 64] = acc[r][1];
    }
}

// ---------------- CSR gather for conv (128 feats) + self-loop + bias + BN + ReLU ----------------
__global__ __launch_bounds__(256) void k_conv_gather(
    const float* __restrict__ hc, const float* __restrict__ deg,
    const int* __restrict__ off, const int* __restrict__ csr_src, const float* __restrict__ csr_w,
    const float* __restrict__ cb,
    const float* __restrict__ g, const float* __restrict__ bb,
    const float* __restrict__ m, const float* __restrict__ v,
    float* __restrict__ cmat)
{
    const int t = threadIdx.x;
    const int node = blockIdx.x * 4 + (t >> 6);   // grid = NN/4
    const int f = (t & 63) * 2;
    const float dg = deg[node];
    const float dinv = 1.0f / dg;
    const float2 self = *reinterpret_cast<const float2*>(&hc[(size_t)node * 128 + f]);
    float ax = fmaf(self.x, dinv, cb[f]);
    float ay = fmaf(self.y, dinv, cb[f + 1]);
    const int beg = off[node];
    const int end = beg + ((int)dg - 1);
    for (int s = beg; s < end; ++s) {
        const int src = csr_src[s];
        const float w = csr_w[s];
        const float2 h = *reinterpret_cast<const float2*>(&hc[(size_t)src * 128 + f]);
        ax = fmaf(h.x, w, ax);
        ay = fmaf(h.y, w, ay);
    }
    const float sc0 = rsqrtf(v[f] + BN_EPS) * g[f];
    const float sh0 = bb[f] - m[f] * sc0;
    const float sc1 = rsqrtf(v[f + 1] + BN_EPS) * g[f + 1];
    const float sh1 = bb[f + 1] - m[f + 1] * sc1;
    float2 o;
    o.x = fmaxf(fmaf(ax, sc0, sh0), 0.f);
    o.y = fmaxf(fmaf(ay, sc1, sh1), 0.f);
    *reinterpret_cast<float2*>(&cmat[(size_t)node * 128 + f]) = o;
}

// ---------------- mean|logvar projection: c[N,128] @ [mw|lw][128,16+16] -> m2 ----------------
__global__ __launch_bounds__(256) void k_mlp_proj(
    const float* __restrict__ c, const float* __restrict__ mw, const float* __restrict__ lw,
    float* __restrict__ m2)
{
    __shared__ float cs[32 * 128];
    const int t = threadIdx.x;
    const int row0 = blockIdx.x * 32;
    const int j0 = t & 15;
    const int r0 = (t >> 4) * 2;
    float acc[2][2] = {};
    for (int idx = t; idx < 1024; idx += 256) {
        const int r = idx >> 5, c4 = idx & 31;
        *reinterpret_cast<float4*>(&cs[r * 128 + c4 * 4]) =
            *reinterpret_cast<const float4*>(&c[(size_t)(row0 + r) * 128 + c4 * 4]);
    }
    __syncthreads();
    #pragma unroll 1
    for (int k = 0; k < 128; k += 4) {
        float wv[4][2];
        #pragma unroll
        for (int kk = 0; kk < 4; ++kk) {
            wv[kk][0] = mw[(k + kk) * 16 + j0];
            wv[kk][1] = lw[(k + kk) * 16 + j0];
        }
        #pragma unroll
        for (int r = 0; r < 2; ++r) {
            const float4 xv = *reinterpret_cast<const float4*>(&cs[(r0 + r) * 128 + k]);
            const float xa[4] = {xv.x, xv.y, xv.z, xv.w};
            #pragma unroll
            for (int kk = 0; kk < 4; ++kk) {
                acc[r][0] = fmaf(xa[kk], wv[kk][0], acc[r][0]);
                acc[r][1] = fmaf(xa[kk], wv[kk][1], acc[r][1]);
            }
        }
    }
    #pragma unroll
    for (int r = 0; r < 2; ++r) {
        const size_t rowi = row0 + r0 + r;
        m2[rowi * 32 + j0] = acc[r][0];
        m2[rowi * 32 + 16 + j0] = acc[r][1];
    }
}

// ---------------- CSR gather for mean|logvar (32 feats) + self-loop + bias ----------------
__global__ __launch_bounds__(256) void k_mlp_gather(
    const float* __restrict__ m2, const float* __restrict__ deg,
    const int* __restrict__ off, const int* __restrict__ csr_src, const float* __restrict__ csr_w,
    const float* __restrict__ mb, const float* __restrict__ lb,
    float* __restrict__ agg2)
{
    const int t = threadIdx.x;
    const int node = blockIdx.x * 8 + (t >> 5);   // grid = NN/8
    const int lane = t & 31;
    const float dg = deg[node];
    const float dinv = 1.0f / dg;
    const float bias = (lane < 16) ? mb[lane] : lb[lane - 16];
    float acc = fmaf(m2[(size_t)node * 32 + lane], dinv, bias);
    const int beg = off[node];
    const int end = beg + ((int)dg - 1);
    for (int s = beg; s < end; ++s) {
        const int src = csr_src[s];
        const float w = csr_w[s];
        acc = fmaf(m2[(size_t)src * 32 + lane], w, acc);
    }
    agg2[(size_t)node * 32 + lane] = acc;
}

// ---------------- finalize: mu/logvar/z writes, dec0, dec1, q ----------------
__global__ __launch_bounds__(256) void k_final(
    const float* __restrict__ feat, const float* __restrict__ agg2,
    const float* __restrict__ d0w, const float* __restrict__ d0b,
    const float* __restrict__ g, const float* __restrict__ bb,
    const float* __restrict__ m, const float* __restrict__ v,
    const float* __restrict__ d1w, const float* __restrict__ d1b,
    const float* __restrict__ cluster,
    float* __restrict__ out)
{
    __shared__ float zs[8][80];
    __shared__ float d0s[8][64];
    __shared__ float qs[8][15];
    const int t = threadIdx.x;
    const int row0 = blockIdx.x * 8;

    for (int idx = t; idx < 512; idx += 256) {
        const int r = idx >> 6, k = idx & 63;
        zs[r][k] = feat[(size_t)(row0 + r) * 64 + k];
    }
    if (t < 128) {
        const int r = t >> 4, k = t & 15;
        const size_t rowi = row0 + r;
        const float muv = agg2[rowi * 32 + k];
        const float lv = agg2[rowi * 32 + 16 + k];
        zs[r][64 + k] = muv;
        out[OMU + rowi * 16 + k] = muv;
        out[OGZ + rowi * 16 + k] = muv;
        out[OZ + rowi * 80 + 64 + k] = muv;
        out[OLV + rowi * 16 + k] = lv;
    }
    __syncthreads();

    // dec0: d0 = ELU(BN(z @ d0w + d0b))
    for (int idx = t; idx < 512; idx += 256) {
        const int r = idx >> 6, n = idx & 63;
        float acc = 0.f;
        #pragma unroll
        for (int k = 0; k < 80; k += 4) {
            const float4 zv = *reinterpret_cast<const float4*>(&zs[r][k]);
            acc = fmaf(zv.x, d0w[(k + 0) * 64 + n], acc);
            acc = fmaf(zv.y, d0w[(k + 1) * 64 + n], acc);
            acc = fmaf(zv.z, d0w[(k + 2) * 64 + n], acc);
            acc = fmaf(zv.w, d0w[(k + 3) * 64 + n], acc);
        }
        acc += d0b[n];
        const float sc = rsqrtf(v[n] + BN_EPS) * g[n];
        d0s[r][n] = elu_f((acc - m[n]) * sc + bb[n]);
    }
    __syncthreads();

    // dec1: de_feat = d0 @ d1w + d1b
    float accC[8][4];
    #pragma unroll
    for (int r = 0; r < 8; ++r) {
        #pragma unroll
        for (int c = 0; c < 4; ++c) accC[r][c] = 0.f;
    }
    int colc[4];
    #pragma unroll
    for (int cj = 0; cj < 4; ++cj) {
        const int col = t + 256 * cj;
        colc[cj] = col < DIN ? col : DIN - 1;
    }
    #pragma unroll 1
    for (int n4 = 0; n4 < 64; n4 += 4) {
        float da[8][4];
        #pragma unroll
        for (int r = 0; r < 8; ++r) {
            const float4 dv = *reinterpret_cast<const float4*>(&d0s[r][n4]);
            da[r][0] = dv.x; da[r][1] = dv.y; da[r][2] = dv.z; da[r][3] = dv.w;
        }
        #pragma unroll
        for (int kk = 0; kk < 4; ++kk) {
            float wv[4];
            #pragma unroll
            for (int cj = 0; cj < 4; ++cj)
                wv[cj] = d1w[(size_t)(n4 + kk) * DIN + colc[cj]];
            #pragma unroll
            for (int r = 0; r < 8; ++r) {
                #pragma unroll
                for (int cj = 0; cj < 4; ++cj)
                    accC[r][cj] = fmaf(da[r][kk], wv[cj], accC[r][cj]);
            }
        }
    }
    #pragma unroll
    for (int cj = 0; cj < 4; ++cj) {
        const int col = t + 256 * cj;
        if (col < DIN) {
            const float bv = d1b[col];
            #pragma unroll
            for (int r = 0; r < 8; ++r)
                out[ODE + (size_t)(row0 + r) * DIN + col] = accC[r][cj] + bv;
        }
    }

    // student-t q
    if (t < 120) {
        const int r = t / 15, c = t % 15;
        float zz = 0.f, cc = 0.f, dot = 0.f;
        #pragma unroll 1
        for (int k = 0; k < 80; ++k) {
            const float zv = zs[r][k];
            const float cv = cluster[c * 80 + k];
            zz = fmaf(zv, zv, zz);
            cc = fmaf(cv, cv, cc);
            dot = fmaf(zv, cv, dot);
        }
        const float dist = fmaxf(zz + cc - 2.f * dot, 0.f);
        qs[r][c] = powf(1.0f / (1.0f + dist / 0.9f + 1e-8f), 0.95f);
    }
    __syncthreads();
    if (t < 120) {
        const int r = t / 15, c = t % 15;
        float s = 0.f;
        #pragma unroll
        for (int c2 = 0; c2 < 15; ++c2) s += qs[r][c2];
        out[OQ + (size_t)(row0 + r) * 15 + c] = qs[r][c] / s;
    }
}

extern "C" void kernel_launch(void* const* d_in, const int* in_sizes, int n_in,
                              void* d_out, int out_size, void* d_ws, size_t ws_size,
                              hipStream_t stream)
{
    const float* x       = (const float*)d_in[0];
    const void*  ei      = d_in[1];
    const float* enc0_w  = (const float*)d_in[2];
    const float* enc0_b  = (const float*)d_in[3];
    const float* enc0_g  = (const float*)d_in[4];
    const float* enc0_bb = (const float*)d_in[5];
    const float* enc0_m  = (const float*)d_in[6];
    const float* enc0_v  = (const float*)d_in[7];
    const float* enc1_w  = (const float*)d_in[8];
    const float* enc1_b  = (const float*)d_in[9];
    const float* enc1_g  = (const float*)d_in[10];
    const float* enc1_bb = (const float*)d_in[11];
    const float* enc1_m  = (const float*)d_in[12];
    const float* enc1_v  = (const float*)d_in[13];
    const float* conv_w  = (const float*)d_in[14];
    const float* conv_b  = (const float*)d_in[15];
    const float* conv_g  = (const float*)d_in[16];
    const float* conv_bb = (const float*)d_in[17];
    const float* conv_m  = (const float*)d_in[18];
    const float* conv_v  = (const float*)d_in[19];
    const float* mean_w  = (const float*)d_in[20];
    const float* mean_b  = (const float*)d_in[21];
    const float* logvar_w = (const float*)d_in[22];
    const float* logvar_b = (const float*)d_in[23];
    const float* dec0_w  = (const float*)d_in[24];
    const float* dec0_b  = (const float*)d_in[25];
    const float* dec0_g  = (const float*)d_in[26];
    const float* dec0_bb = (const float*)d_in[27];
    const float* dec0_m  = (const float*)d_in[28];
    const float* dec0_v  = (const float*)d_in[29];
    const float* dec1_w  = (const float*)d_in[30];
    const float* dec1_b  = (const float*)d_in[31];
    const float* cluster = (const float*)d_in[32];

    float* ws = (float*)d_ws;
    float* deg  = ws;                              // N
    float* feat = ws + NN;                         // 64N
    float* A    = ws + (size_t)65 * NN;            // 256N: h1 | hc+cmat | m2+agg2
    size_t base = (size_t)321 * NN;
    int*   off     = (int*)(ws + base);                       // N
    int*   cursor  = (int*)(ws + base + NN);                  // N
    int*   bsum    = (int*)(ws + base + 2 * (size_t)NN);      // 512
    int*   csr_src = (int*)(ws + base + 2 * (size_t)NN + 512);            // E
    float* csr_w   = (float*)(ws + base + 2 * (size_t)NN + 512 + NE);     // E
    int*   flag    = (int*)(ws + base + 2 * (size_t)NN + 512 + 2 * (size_t)NE); // 1

    float* h1   = A;                      // N x 256
    float* hc   = A;                      // N x 128 (after h1 dead)
    float* cmat = A + (size_t)128 * NN;   // N x 128
    float* m2   = A;                      // N x 32 (after hc dead)
    float* agg2 = A + (size_t)32 * NN;    // N x 32

    float* out = (float*)d_out;

    k_detect<<<1, 256, 0, stream>>>((const int*)ei, flag);
    k_deg_init<<<NB, 256, 0, stream>>>(deg);
    k_deg_accum<<<NE / 256, 256, 0, stream>>>(ei, flag, deg);

    // CSR build
    k_scan1<<<NB, 256, 0, stream>>>(deg, off, bsum, cursor);
    k_scan2<<<1, 512, 0, stream>>>(bsum);
    k_scan3<<<NB, 256, 0, stream>>>(off, bsum);
    k_fill<<<NE / 256, 256, 0, stream>>>(ei, flag, deg, off, cursor, csr_src, csr_w);

    k_enc0<<<NN / 32, 256, 0, stream>>>(x, enc0_w, enc0_b, enc0_g, enc0_bb, enc0_m, enc0_v, h1);
    k_enc1<<<NN / 32, 256, 0, stream>>>(h1, enc1_w, enc1_b, enc1_g, enc1_bb, enc1_m, enc1_v, feat, out);

    k_conv_proj<<<NN / 32, 256, 0, stream>>>(feat, conv_w, hc);
    k_conv_gather<<<NN / 4, 256, 0, stream>>>(hc, deg, off, csr_src, csr_w, conv_b,
                                              conv_g, conv_bb, conv_m, conv_v, cmat);

    k_mlp_proj<<<NN / 32, 256, 0, stream>>>(cmat, mean_w, logvar_w, m2);
    k_mlp_gather<<<NN / 8, 256, 0, stream>>>(m2, deg, off, csr_src, csr_w, mean_b, logvar_b, agg2);

    k_final<<<NN / 8, 256, 0, stream>>>(feat, agg2, dec0_w, dec0_b, dec0_g, dec0_bb, dec0_m, dec0_v,
                                        dec1_w, dec1_b, cluster, out);
}

// Round 7
// 1268.731 us; speedup vs baseline: 3.7966x; 1.4125x over previous
//
#include <hip/hip_runtime.h>
#include <hip/hip_bf16.h>

#define NN 100000
#define NE 1600000
#define DIN 1000
#define BN_EPS 1e-3f
#define NB 391   // ceil(NN/256)

// output element offsets (concat of z, mu, logvar, de_feat, q, feat_x, gnn_z) — float32 out
#define OZ  ((size_t)0)
#define OMU ((size_t)NN*80)
#define OLV ((size_t)NN*96)
#define ODE ((size_t)NN*112)
#define OQ  ((size_t)NN*1112)
#define OFX ((size_t)NN*1127)
#define OGZ ((size_t)NN*1191)

typedef __attribute__((ext_vector_type(8))) short short8v;   // 8 bf16 (4 VGPRs)
typedef __attribute__((ext_vector_type(4))) float f32x4;     // MFMA accumulator

__device__ __forceinline__ float elu_f(float x) { return x > 0.f ? x : expf(x) - 1.f; }

// fp32 -> bf16 bits, round-to-nearest-even
__device__ __forceinline__ short f2bf(float f) {
    union { float f; unsigned u; } c; c.f = f;
    unsigned r = c.u + 0x7fffu + ((c.u >> 16) & 1u);
    return (short)(r >> 16);
}

// Edge index may arrive as int32 or int64; logical element idx in flat (2*E) array.
__device__ __forceinline__ int edge_at(const void* ei, int is64, size_t idx) {
    if (is64) return (int)((const long long*)ei)[idx];
    return ((const int*)ei)[idx];
}

// ---------------- dtype detection ----------------
__global__ __launch_bounds__(256) void k_detect(const int* __restrict__ ei, int* __restrict__ flag) {
    __shared__ int nz;
    if (threadIdx.x == 0) nz = 0;
    __syncthreads();
    for (int i = threadIdx.x; i < 2048; i += 256)
        if (ei[2 * i + 1] != 0) nz = 1;
    __syncthreads();
    if (threadIdx.x == 0) flag[0] = (nz == 0) ? 1 : 0;  // 1 => int64
}

// ---------------- degree ----------------
__global__ __launch_bounds__(256) void k_deg_init(float* __restrict__ deg) {
    int i = blockIdx.x * 256 + threadIdx.x;
    if (i < NN) deg[i] = 1.0f;
}

__global__ __launch_bounds__(256) void k_deg_accum(const void* __restrict__ ei, const int* __restrict__ flag,
                                                   float* __restrict__ deg) {
    const int is64 = flag[0];
    int e = blockIdx.x * 256 + threadIdx.x;
    if (e < NE) atomicAdd(&deg[edge_at(ei, is64, (size_t)NE + e)], 1.0f);
}

// ---------------- CSR build: exclusive scan of in-edge counts ----------------
__global__ __launch_bounds__(256) void k_scan1(const float* __restrict__ deg, int* __restrict__ off,
                                               int* __restrict__ bsum, int* __restrict__ cursor) {
    __shared__ int s[256];
    const int t = threadIdx.x;
    const int i = blockIdx.x * 256 + t;
    const int vv = (i < NN) ? ((int)deg[i]) - 1 : 0;
    if (i < NN) cursor[i] = 0;
    s[t] = vv;
    __syncthreads();
    for (int d = 1; d < 256; d <<= 1) {
        const int u = (t >= d) ? s[t - d] : 0;
        __syncthreads();
        s[t] += u;
        __syncthreads();
    }
    if (i < NN) off[i] = s[t] - vv;           // exclusive, pre-block-offset
    if (t == 255) bsum[blockIdx.x] = s[t];    // block total
}

__global__ __launch_bounds__(512) void k_scan2(int* __restrict__ bsum) {
    __shared__ int s[512];
    const int t = threadIdx.x;
    const int vv = (t < NB) ? bsum[t] : 0;
    s[t] = vv;
    __syncthreads();
    for (int d = 1; d < 512; d <<= 1) {
        const int u = (t >= d) ? s[t - d] : 0;
        __syncthreads();
        s[t] += u;
        __syncthreads();
    }
    if (t < NB) bsum[t] = s[t] - vv;          // exclusive block prefix
}

__global__ __launch_bounds__(256) void k_scan3(int* __restrict__ off, const int* __restrict__ bsum) {
    const int i = blockIdx.x * 256 + threadIdx.x;
    if (i < NN) off[i] += bsum[blockIdx.x];
}

__global__ __launch_bounds__(256) void k_fill(const void* __restrict__ ei, const int* __restrict__ flag,
                                              const float* __restrict__ deg, const int* __restrict__ off,
                                              int* __restrict__ cursor,
                                              int* __restrict__ csr_src, float* __restrict__ csr_w) {
    const int is64 = flag[0];
    const int e = blockIdx.x * 256 + threadIdx.x;
    if (e >= NE) return;
    const int r = edge_at(ei, is64, e);
    const int c = edge_at(ei, is64, (size_t)NE + e);
    const float w = rsqrtf(deg[r]) * rsqrtf(deg[c]);
    const int p = atomicAdd(&cursor[c], 1);
    const int slot = off[c] + p;
    csr_src[slot] = r;
    csr_w[slot] = w;
}

// ---------------- weight transpose+convert: w[1000][256] f32 -> w_t[256][1024] bf16 (K zero-padded) ----------------
__global__ __launch_bounds__(256) void k_wt(const float* __restrict__ w, short* __restrict__ wt) {
    const int tid = blockIdx.x * 256 + threadIdx.x;   // 256*1024 elements
    const int c = tid >> 10;
    const int k = tid & 1023;
    wt[(size_t)c * 1024 + k] = (k < DIN) ? f2bf(w[(size_t)k * 256 + c]) : (short)0;
}

// ---------------- encoder L0 via MFMA: h1 = ELU(BN(x @ w)) ----------------
// Block tile 128x128, 4 waves 2x2, wave tile 64x64 (4x4 frags of 16x16), K_STEP=32.
// LDS layout: 16B granules g(kc,row) = kc*128+row holding 8 bf16 (k-chunk kc*8..+8).
__global__ __launch_bounds__(256, 2) void k_enc0_mfma(
    const float* __restrict__ x, const short* __restrict__ wt, const float* __restrict__ bias,
    const float* __restrict__ g, const float* __restrict__ bb,
    const float* __restrict__ m, const float* __restrict__ v,
    float* __restrict__ h1)
{
    __shared__ short As[4 * 128 * 8];
    __shared__ short Bs[4 * 128 * 8];
    const int t = threadIdx.x;
    const int lane = t & 63;
    const int wave = t >> 6;
    const int wm = (wave >> 1) * 64;
    const int wn = (wave & 1) * 64;
    const int row0 = blockIdx.x * 128;
    const int col0 = blockIdx.y * 128;

    f32x4 acc[4][4];
    #pragma unroll
    for (int mi = 0; mi < 4; ++mi)
        #pragma unroll
        for (int ni = 0; ni < 4; ++ni)
            acc[mi][ni] = (f32x4){0.f, 0.f, 0.f, 0.f};

    const int srow = t >> 1;     // 0..127
    const int skc2 = t & 1;      // k-half: offset 16*skc2
    const bool arow_ok = (row0 + srow) < NN;
    const float* xrow = x + (size_t)(row0 + srow) * DIN;
    const short* wtrow = wt + (size_t)(col0 + srow) * 1024;

    const int kc = lane >> 4;    // 0..3
    const int lr = lane & 15;

    for (int ks = 0; ks < 32; ++ks) {
        const int k0 = ks * 32;
        __syncthreads();
        // ---- stage A (x -> bf16), 16 k per thread ----
        {
            short tmp[16];
            const int kbase = k0 + skc2 * 16;
            if (arow_ok) {
                if (kbase + 16 <= DIN) {
                    #pragma unroll
                    for (int q = 0; q < 4; ++q) {
                        const float4 fv = *reinterpret_cast<const float4*>(xrow + kbase + q * 4);
                        tmp[q * 4 + 0] = f2bf(fv.x);
                        tmp[q * 4 + 1] = f2bf(fv.y);
                        tmp[q * 4 + 2] = f2bf(fv.z);
                        tmp[q * 4 + 3] = f2bf(fv.w);
                    }
                } else {
                    #pragma unroll
                    for (int j = 0; j < 16; ++j) {
                        const int k = kbase + j;
                        tmp[j] = (k < DIN) ? f2bf(xrow[k]) : (short)0;
                    }
                }
            } else {
                #pragma unroll
                for (int j = 0; j < 16; ++j) tmp[j] = 0;
            }
            short8v p0, p1;
            #pragma unroll
            for (int j = 0; j < 8; ++j) { p0[j] = tmp[j]; p1[j] = tmp[8 + j]; }
            *reinterpret_cast<short8v*>(&As[((skc2 * 2 + 0) * 128 + srow) * 8]) = p0;
            *reinterpret_cast<short8v*>(&As[((skc2 * 2 + 1) * 128 + srow) * 8]) = p1;
        }
        // ---- stage B (w_t already bf16, K padded) ----
        {
            const short8v g0 = *reinterpret_cast<const short8v*>(wtrow + k0 + skc2 * 16);
            const short8v g1 = *reinterpret_cast<const short8v*>(wtrow + k0 + skc2 * 16 + 8);
            *reinterpret_cast<short8v*>(&Bs[((skc2 * 2 + 0) * 128 + srow) * 8]) = g0;
            *reinterpret_cast<short8v*>(&Bs[((skc2 * 2 + 1) * 128 + srow) * 8]) = g1;
        }
        __syncthreads();
        // ---- fragments + MFMA ----
        short8v a[4], b[4];
        #pragma unroll
        for (int mi = 0; mi < 4; ++mi)
            a[mi] = *reinterpret_cast<const short8v*>(&As[(kc * 128 + wm + mi * 16 + lr) * 8]);
        #pragma unroll
        for (int ni = 0; ni < 4; ++ni)
            b[ni] = *reinterpret_cast<const short8v*>(&Bs[(kc * 128 + wn + ni * 16 + lr) * 8]);
        #pragma unroll
        for (int mi = 0; mi < 4; ++mi)
            #pragma unroll
            for (int ni = 0; ni < 4; ++ni)
                acc[mi][ni] = __builtin_amdgcn_mfma_f32_16x16x32_bf16(a[mi], b[ni], acc[mi][ni], 0, 0, 0);
    }

    // ---- epilogue: BN + ELU, C/D layout col=lane&15, row=(lane>>4)*4+reg ----
    float sc[4], sh[4];
    int cols[4];
    #pragma unroll
    for (int ni = 0; ni < 4; ++ni) {
        const int col = col0 + wn + ni * 16 + lr;
        cols[ni] = col;
        const float s = rsqrtf(v[col] + BN_EPS) * g[col];
        sc[ni] = s;
        sh[ni] = (bias[col] - m[col]) * s + bb[col];
    }
    #pragma unroll
    for (int mi = 0; mi < 4; ++mi) {
        #pragma unroll
        for (int j = 0; j < 4; ++j) {
            const int row = row0 + wm + mi * 16 + (lane >> 4) * 4 + j;
            if (row < NN) {
                #pragma unroll
                for (int ni = 0; ni < 4; ++ni) {
                    const float y = acc[mi][ni][j] * sc[ni] + sh[ni];
                    h1[(size_t)row * 256 + cols[ni]] = elu_f(y);
                }
            }
        }
    }
}

// ---------------- encoder L1: h1[N,256] @ w[256,64] + BN + ELU -> feat, out ----------------
__global__ __launch_bounds__(256) void k_enc1(
    const float* __restrict__ h1, const float* __restrict__ w, const float* __restrict__ bias,
    const float* __restrict__ g, const float* __restrict__ bb,
    const float* __restrict__ m, const float* __restrict__ v,
    float* __restrict__ feat, float* __restrict__ out)
{
    __shared__ float hs[32 * 256];
    const int t = threadIdx.x;
    const int row0 = blockIdx.x * 32;
    const int j0 = t & 31;
    const int r0 = (t >> 5) * 4;
    float acc[4][2] = {};
    for (int idx = t; idx < 2048; idx += 256) {
        const int r = idx >> 6, c4 = idx & 63;
        *reinterpret_cast<float4*>(&hs[r * 256 + c4 * 4]) =
            *reinterpret_cast<const float4*>(&h1[(size_t)(row0 + r) * 256 + c4 * 4]);
    }
    __syncthreads();
    #pragma unroll 1
    for (int k = 0; k < 256; k += 4) {
        float wv[4][2];
        #pragma unroll
        for (int kk = 0; kk < 4; ++kk) {
            wv[kk][0] = w[(k + kk) * 64 + j0];
            wv[kk][1] = w[(k + kk) * 64 + j0 + 32];
        }
        #pragma unroll
        for (int r = 0; r < 4; ++r) {
            const float4 xv = *reinterpret_cast<const float4*>(&hs[(r0 + r) * 256 + k]);
            const float xa[4] = {xv.x, xv.y, xv.z, xv.w};
            #pragma unroll
            for (int kk = 0; kk < 4; ++kk) {
                acc[r][0] = fmaf(xa[kk], wv[kk][0], acc[r][0]);
                acc[r][1] = fmaf(xa[kk], wv[kk][1], acc[r][1]);
            }
        }
    }
    #pragma unroll
    for (int c = 0; c < 2; ++c) {
        const int j = j0 + 32 * c;
        const float sc = rsqrtf(v[j] + BN_EPS) * g[j];
        const float sh = (bias[j] - m[j]) * sc + bb[j];
        #pragma unroll
        for (int r = 0; r < 4; ++r) {
            const size_t rowi = row0 + r0 + r;
            const float y = elu_f(acc[r][c] * sc + sh);
            feat[rowi * 64 + j] = y;
            out[OFX + rowi * 64 + j] = y;
            out[OZ + rowi * 80 + j] = y;
        }
    }
}

// ---------------- GCN projection: feat[N,64] @ conv_w[64,128] -> hc ----------------
__global__ __launch_bounds__(256) void k_conv_proj(
    const float* __restrict__ feat, const float* __restrict__ w,
    float* __restrict__ hc)
{
    __shared__ float fs[32 * 64];
    const int t = threadIdx.x;
    const int row0 = blockIdx.x * 32;
    const int j0 = t & 63;
    const int r0 = (t >> 6) * 8;
    float acc[8][2] = {};
    for (int idx = t; idx < 512; idx += 256) {
        const int r = idx >> 4, c4 = idx & 15;
        *reinterpret_cast<float4*>(&fs[r * 64 + c4 * 4]) =
            *reinterpret_cast<const float4*>(&feat[(size_t)(row0 + r) * 64 + c4 * 4]);
    }
    __syncthreads();
    #pragma unroll 1
    for (int k = 0; k < 64; k += 4) {
        float wv[4][2];
        #pragma unroll
        for (int kk = 0; kk < 4; ++kk) {
            wv[kk][0] = w[(k + kk) * 128 + j0];
            wv[kk][1] = w[(k + kk) * 128 + j0 + 64];
        }
        #pragma unroll
        for (int r = 0; r < 8; ++r) {
            const float4 xv = *reinterpret_cast<const float4*>(&fs[(r0 + r) * 64 + k]);
            const float xa[4] = {xv.x, xv.y, xv.z, xv.w};
            #pragma unroll
            for (int kk = 0; kk < 4; ++kk) {
                acc[r][0] = fmaf(xa[kk], wv[kk][0], acc[r][0]);
                acc[r][1] = fmaf(xa[kk], wv[kk][1], acc[r][1]);
            }
        }
    }
    #pragma unroll
    for (int r = 0; r < 8; ++r) {
        const size_t rowi = row0 + r0 + r;
        hc[rowi * 128 + j0] = acc[r][0];
        hc[rowi * 128 + j0 + 64] = acc[r][1];
    }
}

// ---------------- CSR gather for conv (128 feats) + self-loop + bias + BN + ReLU ----------------
__global__ __launch_bounds__(256) void k_conv_gather(
    const float* __restrict__ hc, const float* __restrict__ deg,
    const int* __restrict__ off, const int* __restrict__ csr_src, const float* __restrict__ csr_w,
    const float* __restrict__ cb,
    const float* __restrict__ g, const float* __restrict__ bb,
    const float* __restrict__ m, const float* __restrict__ v,
    float* __restrict__ cmat)
{
    const int t = threadIdx.x;
    const int node = blockIdx.x * 4 + (t >> 6);   // grid = NN/4
    const int f = (t & 63) * 2;
    const float dg = deg[node];
    const float dinv = 1.0f / dg;
    const float2 self = *reinterpret_cast<const float2*>(&hc[(size_t)node * 128 + f]);
    float ax = fmaf(self.x, dinv, cb[f]);
    float ay = fmaf(self.y, dinv, cb[f + 1]);
    const int beg = off[node];
    const int end = beg + ((int)dg - 1);
    for (int s = beg; s < end; ++s) {
        const int src = csr_src[s];
        const float w = csr_w[s];
        const float2 h = *reinterpret_cast<const float2*>(&hc[(size_t)src * 128 + f]);
        ax = fmaf(h.x, w, ax);
        ay = fmaf(h.y, w, ay);
    }
    const float sc0 = rsqrtf(v[f] + BN_EPS) * g[f];
    const float sh0 = bb[f] - m[f] * sc0;
    const float sc1 = rsqrtf(v[f + 1] + BN_EPS) * g[f + 1];
    const float sh1 = bb[f + 1] - m[f + 1] * sc1;
    float2 o;
    o.x = fmaxf(fmaf(ax, sc0, sh0), 0.f);
    o.y = fmaxf(fmaf(ay, sc1, sh1), 0.f);
    *reinterpret_cast<float2*>(&cmat[(size_t)node * 128 + f]) = o;
}

// ---------------- mean|logvar projection: c[N,128] @ [mw|lw][128,16+16] -> m2 ----------------
__global__ __launch_bounds__(256) void k_mlp_proj(
    const float* __restrict__ c, const float* __restrict__ mw, const float* __restrict__ lw,
    float* __restrict__ m2)
{
    __shared__ float cs[32 * 128];
    const int t = threadIdx.x;
    const int row0 = blockIdx.x * 32;
    const int j0 = t & 15;
    const int r0 = (t >> 4) * 2;
    float acc[2][2] = {};
    for (int idx = t; idx < 1024; idx += 256) {
        const int r = idx >> 5, c4 = idx & 31;
        *reinterpret_cast<float4*>(&cs[r * 128 + c4 * 4]) =
            *reinterpret_cast<const float4*>(&c[(size_t)(row0 + r) * 128 + c4 * 4]);
    }
    __syncthreads();
    #pragma unroll 1
    for (int k = 0; k < 128; k += 4) {
        float wv[4][2];
        #pragma unroll
        for (int kk = 0; kk < 4; ++kk) {
            wv[kk][0] = mw[(k + kk) * 16 + j0];
            wv[kk][1] = lw[(k + kk) * 16 + j0];
        }
        #pragma unroll
        for (int r = 0; r < 2; ++r) {
            const float4 xv = *reinterpret_cast<const float4*>(&cs[(r0 + r) * 128 + k]);
            const float xa[4] = {xv.x, xv.y, xv.z, xv.w};
            #pragma unroll
            for (int kk = 0; kk < 4; ++kk) {
                acc[r][0] = fmaf(xa[kk], wv[kk][0], acc[r][0]);
                acc[r][1] = fmaf(xa[kk], wv[kk][1], acc[r][1]);
            }
        }
    }
    #pragma unroll
    for (int r = 0; r < 2; ++r) {
        const size_t rowi = row0 + r0 + r;
        m2[rowi * 32 + j0] = acc[r][0];
        m2[rowi * 32 + 16 + j0] = acc[r][1];
    }
}

// ---------------- CSR gather for mean|logvar (32 feats) + self-loop + bias ----------------
__global__ __launch_bounds__(256) void k_mlp_gather(
    const float* __restrict__ m2, const float* __restrict__ deg,
    const int* __restrict__ off, const int* __restrict__ csr_src, const float* __restrict__ csr_w,
    const float* __restrict__ mb, const float* __restrict__ lb,
    float* __restrict__ agg2)
{
    const int t = threadIdx.x;
    const int node = blockIdx.x * 8 + (t >> 5);   // grid = NN/8
    const int lane = t & 31;
    const float dg = deg[node];
    const float dinv = 1.0f / dg;
    const float bias = (lane < 16) ? mb[lane] : lb[lane - 16];
    float acc = fmaf(m2[(size_t)node * 32 + lane], dinv, bias);
    const int beg = off[node];
    const int end = beg + ((int)dg - 1);
    for (int s = beg; s < end; ++s) {
        const int src = csr_src[s];
        const float w = csr_w[s];
        acc = fmaf(m2[(size_t)src * 32 + lane], w, acc);
    }
    agg2[(size_t)node * 32 + lane] = acc;
}

// ---------------- finalize: mu/logvar/z writes, dec0, dec1, q ----------------
__global__ __launch_bounds__(256) void k_final(
    const float* __restrict__ feat, const float* __restrict__ agg2,
    const float* __restrict__ d0w, const float* __restrict__ d0b,
    const float* __restrict__ g, const float* __restrict__ bb,
    const float* __restrict__ m, const float* __restrict__ v,
    const float* __restrict__ d1w, const float* __restrict__ d1b,
    const float* __restrict__ cluster,
    float* __restrict__ out)
{
    __shared__ float zs[8][80];
    __shared__ float d0s[8][64];
    __shared__ float qs[8][15];
    const int t = threadIdx.x;
    const int row0 = blockIdx.x * 8;

    for (int idx = t; idx < 512; idx += 256) {
        const int r = idx >> 6, k = idx & 63;
        zs[r][k] = feat[(size_t)(row0 + r) * 64 + k];
    }
    if (t < 128) {
        const int r = t >> 4, k = t & 15;
        const size_t rowi = row0 + r;
        const float muv = agg2[rowi * 32 + k];
        const float lv = agg2[rowi * 32 + 16 + k];
        zs[r][64 + k] = muv;
        out[OMU + rowi * 16 + k] = muv;
        out[OGZ + rowi * 16 + k] = muv;
        out[OZ + rowi * 80 + 64 + k] = muv;
        out[OLV + rowi * 16 + k] = lv;
    }
    __syncthreads();

    // dec0: d0 = ELU(BN(z @ d0w + d0b))
    for (int idx = t; idx < 512; idx += 256) {
        const int r = idx >> 6, n = idx & 63;
        float acc = 0.f;
        #pragma unroll
        for (int k = 0; k < 80; k += 4) {
            const float4 zv = *reinterpret_cast<const float4*>(&zs[r][k]);
            acc = fmaf(zv.x, d0w[(k + 0) * 64 + n], acc);
            acc = fmaf(zv.y, d0w[(k + 1) * 64 + n], acc);
            acc = fmaf(zv.z, d0w[(k + 2) * 64 + n], acc);
            acc = fmaf(zv.w, d0w[(k + 3) * 64 + n], acc);
        }
        acc += d0b[n];
        const float sc = rsqrtf(v[n] + BN_EPS) * g[n];
        d0s[r][n] = elu_f((acc - m[n]) * sc + bb[n]);
    }
    __syncthreads();

    // dec1: de_feat = d0 @ d1w + d1b
    float accC[8][4];
    #pragma unroll
    for (int r = 0; r < 8; ++r) {
        #pragma unroll
        for (int c = 0; c < 4; ++c) accC[r][c] = 0.f;
    }
    int colc[4];
    #pragma unroll
    for (int cj = 0; cj < 4; ++cj) {
        const int col = t + 256 * cj;
        colc[cj] = col < DIN ? col : DIN - 1;
    }
    #pragma unroll 1
    for (int n4 = 0; n4 < 64; n4 += 4) {
        float da[8][4];
        #pragma unroll
        for (int r = 0; r < 8; ++r) {
            const float4 dv = *reinterpret_cast<const float4*>(&d0s[r][n4]);
            da[r][0] = dv.x; da[r][1] = dv.y; da[r][2] = dv.z; da[r][3] = dv.w;
        }
        #pragma unroll
        for (int kk = 0; kk < 4; ++kk) {
            float wv[4];
            #pragma unroll
            for (int cj = 0; cj < 4; ++cj)
                wv[cj] = d1w[(size_t)(n4 + kk) * DIN + colc[cj]];
            #pragma unroll
            for (int r = 0; r < 8; ++r) {
                #pragma unroll
                for (int cj = 0; cj < 4; ++cj)
                    accC[r][cj] = fmaf(da[r][kk], wv[cj], accC[r][cj]);
            }
        }
    }
    #pragma unroll
    for (int cj = 0; cj < 4; ++cj) {
        const int col = t + 256 * cj;
        if (col < DIN) {
            const float bv = d1b[col];
            #pragma unroll
            for (int r = 0; r < 8; ++r)
                out[ODE + (size_t)(row0 + r) * DIN + col] = accC[r][cj] + bv;
        }
    }

    // student-t q
    if (t < 120) {
        const int r = t / 15, c = t % 15;
        float zz = 0.f, cc = 0.f, dot = 0.f;
        #pragma unroll 1
        for (int k = 0; k < 80; ++k) {
            const float zv = zs[r][k];
            const float cv = cluster[c * 80 + k];
            zz = fmaf(zv, zv, zz);
            cc = fmaf(cv, cv, cc);
            dot = fmaf(zv, cv, dot);
        }
        const float dist = fmaxf(zz + cc - 2.f * dot, 0.f);
        qs[r][c] = powf(1.0f / (1.0f + dist / 0.9f + 1e-8f), 0.95f);
    }
    __syncthreads();
    if (t < 120) {
        const int r = t / 15, c = t % 15;
        float s = 0.f;
        #pragma unroll
        for (int c2 = 0; c2 < 15; ++c2) s += qs[r][c2];
        out[OQ + (size_t)(row0 + r) * 15 + c] = qs[r][c] / s;
    }
}

extern "C" void kernel_launch(void* const* d_in, const int* in_sizes, int n_in,
                              void* d_out, int out_size, void* d_ws, size_t ws_size,
                              hipStream_t stream)
{
    const float* x       = (const float*)d_in[0];
    const void*  ei      = d_in[1];
    const float* enc0_w  = (const float*)d_in[2];
    const float* enc0_b  = (const float*)d_in[3];
    const float* enc0_g  = (const float*)d_in[4];
    const float* enc0_bb = (const float*)d_in[5];
    const float* enc0_m  = (const float*)d_in[6];
    const float* enc0_v  = (const float*)d_in[7];
    const float* enc1_w  = (const float*)d_in[8];
    const float* enc1_b  = (const float*)d_in[9];
    const float* enc1_g  = (const float*)d_in[10];
    const float* enc1_bb = (const float*)d_in[11];
    const float* enc1_m  = (const float*)d_in[12];
    const float* enc1_v  = (const float*)d_in[13];
    const float* conv_w  = (const float*)d_in[14];
    const float* conv_b  = (const float*)d_in[15];
    const float* conv_g  = (const float*)d_in[16];
    const float* conv_bb = (const float*)d_in[17];
    const float* conv_m  = (const float*)d_in[18];
    const float* conv_v  = (const float*)d_in[19];
    const float* mean_w  = (const float*)d_in[20];
    const float* mean_b  = (const float*)d_in[21];
    const float* logvar_w = (const float*)d_in[22];
    const float* logvar_b = (const float*)d_in[23];
    const float* dec0_w  = (const float*)d_in[24];
    const float* dec0_b  = (const float*)d_in[25];
    const float* dec0_g  = (const float*)d_in[26];
    const float* dec0_bb = (const float*)d_in[27];
    const float* dec0_m  = (const float*)d_in[28];
    const float* dec0_v  = (const float*)d_in[29];
    const float* dec1_w  = (const float*)d_in[30];
    const float* dec1_b  = (const float*)d_in[31];
    const float* cluster = (const float*)d_in[32];

    float* ws = (float*)d_ws;
    float* deg  = ws;                              // N
    float* feat = ws + NN;                         // 64N
    float* A    = ws + (size_t)65 * NN;            // 256N: h1 | hc+cmat | m2+agg2
    size_t base = (size_t)321 * NN;
    int*   off     = (int*)(ws + base);                        // N
    int*   cursor  = (int*)(ws + base + NN);                   // N
    int*   bsum    = (int*)(ws + base + 2 * (size_t)NN);       // 512
    int*   csr_src = (int*)(ws + base + 2 * (size_t)NN + 512);             // E
    float* csr_w   = (float*)(ws + base + 2 * (size_t)NN + 512 + NE);      // E
    short* wt      = (short*)(ws + base + 2 * (size_t)NN + 512 + 2 * (size_t)NE);  // 256*1024 bf16 = 131072 floats
    int*   flag    = (int*)(ws + base + 2 * (size_t)NN + 512 + 2 * (size_t)NE + 131072); // 1

    float* h1   = A;                      // N x 256
    float* hc   = A;                      // N x 128 (after h1 dead)
    float* cmat = A + (size_t)128 * NN;   // N x 128
    float* m2   = A;                      // N x 32 (after hc dead)
    float* agg2 = A + (size_t)32 * NN;    // N x 32

    float* out = (float*)d_out;

    k_detect<<<1, 256, 0, stream>>>((const int*)ei, flag);
    k_deg_init<<<NB, 256, 0, stream>>>(deg);
    k_deg_accum<<<NE / 256, 256, 0, stream>>>(ei, flag, deg);

    // CSR build
    k_scan1<<<NB, 256, 0, stream>>>(deg, off, bsum, cursor);
    k_scan2<<<1, 512, 0, stream>>>(bsum);
    k_scan3<<<NB, 256, 0, stream>>>(off, bsum);
    k_fill<<<NE / 256, 256, 0, stream>>>(ei, flag, deg, off, cursor, csr_src, csr_w);

    // enc0 via MFMA
    k_wt<<<1024, 256, 0, stream>>>(enc0_w, wt);
    {
        dim3 grid((NN + 127) / 128, 2);
        k_enc0_mfma<<<grid, 256, 0, stream>>>(x, wt, enc0_b, enc0_g, enc0_bb, enc0_m, enc0_v, h1);
    }
    k_enc1<<<NN / 32, 256, 0, stream>>>(h1, enc1_w, enc1_b, enc1_g, enc1_bb, enc1_m, enc1_v, feat, out);

    k_conv_proj<<<NN / 32, 256, 0, stream>>>(feat, conv_w, hc);
    k_conv_gather<<<NN / 4, 256, 0, stream>>>(hc, deg, off, csr_src, csr_w, conv_b,
                                              conv_g, conv_bb, conv_m, conv_v, cmat);

    k_mlp_proj<<<NN / 32, 256, 0, stream>>>(cmat, mean_w, logvar_w, m2);
    k_mlp_gather<<<NN / 8, 256, 0, stream>>>(m2, deg, off, csr_src, csr_w, mean_b, logvar_b, agg2);

    k_final<<<NN / 8, 256, 0, stream>>>(feat, agg2, dec0_w, dec0_b, dec0_g, dec0_bb, dec0_m, dec0_v,
                                        dec1_w, dec1_b, cluster, out);
}